// Round 3
// baseline (353.059 us; speedup 1.0000x reference)
//
#include <hip/hip_runtime.h>
#include <math.h>
#include <stdint.h>

#define B_ 64
#define J_ 512
#define D_ 1024

typedef __attribute__((ext_vector_type(8))) short short8;
typedef __attribute__((ext_vector_type(4))) float f32x4;

#define GLOBAL_AS __attribute__((address_space(1)))
#define LDS_AS    __attribute__((address_space(3)))

__device__ __forceinline__ void async16(const void* g, void* l) {
    __builtin_amdgcn_global_load_lds((const GLOBAL_AS uint32_t*)g,
                                     (LDS_AS uint32_t*)l, 16, 0, 0);
}

// tanh(x) = 1 - 2/(1+e^{2x}); saturates correctly for |x| large.
__device__ __forceinline__ float fast_tanh(float x) {
    return 1.0f - 2.0f / (1.0f + __expf(2.0f * x));
}

// fp32 -> bf16 round-to-nearest-even
__device__ __forceinline__ unsigned short f2bf(float f) {
    uint32_t u = __builtin_bit_cast(uint32_t, f);
    u += 0x7fffu + ((u >> 16) & 1u);
    return (unsigned short)(u >> 16);
}

__device__ __forceinline__ uint32_t pk2(float a, float b) {
    return (uint32_t)f2bf(a) | ((uint32_t)f2bf(b) << 16);
}

#define FENCE asm volatile("" ::: "memory")

// ---------------------------------------------------------------------------
// prep: W1[k][n] fp32 -> W1t[n][k] bf16, fused with zeroing of pooled accum.
// ---------------------------------------------------------------------------
__global__ __launch_bounds__(256) void prep_kernel(const float* __restrict__ W1,
                                                   unsigned short* __restrict__ W1t,
                                                   float* __restrict__ pooled) {
    __shared__ float t[32][33];
    const int b   = blockIdx.x;
    const int tid = threadIdx.x;
    if (b < 256) pooled[b * 256 + tid] = 0.f;   // 64*1024 floats total
    const int bx = b & 31, by = b >> 5;
    const int tx = tid & 31, ty = tid >> 5;
    const int n = bx * 32 + tx;
    for (int i = ty; i < 32; i += 8)
        t[i][tx] = W1[(size_t)(by * 32 + i) * D_ + n];
    __syncthreads();
    const int k = by * 32 + tx;
    for (int i = ty; i < 32; i += 8)
        W1t[(size_t)(bx * 32 + i) * D_ + k] = f2bf(t[tx][i]);
}

// ---------------------------------------------------------------------------
// Fused cast+gemm+score kernel — round-0 geometry (512 thr, 8 waves, 64x256
// tile, BK=64, wave-tile 64x32) with a counted-vmcnt raw-barrier pipeline:
//   X barrier (WAR) -> publish A via ds_write -> issue A[it+1] reg-load +
//   B[it+1] global_load_lds into other buffer -> s_waitcnt vmcnt(5) (retires
//   exactly B[it], keeps prefetch in flight) -> lgkmcnt(0) -> Y barrier ->
//   16 MFMA. vmcnt never drains to 0 in steady state (T3+T4).
// Sweep 0 (it=0..15) fuses the f32->bf16 cast of x (pack in MFMA shadow,
// write-through to Xb); sweeps 1-3 re-read self-written bf16 Xb.
// ---------------------------------------------------------------------------
__global__ __launch_bounds__(512, 4) void gemm_score_kernel(
    const float* __restrict__ x, unsigned short* __restrict__ Xb,
    const unsigned short* __restrict__ W1t,
    const float* __restrict__ b1, const float* __restrict__ W2,
    const float* __restrict__ b2, const float* __restrict__ mask,
    float* __restrict__ val_ws, float* __restrict__ pooled)
{
    __shared__ __align__(16) unsigned short ldsA[64 * 64];        //  8 KB single
    __shared__ __align__(16) unsigned short ldsB[2 * 256 * 64];   // 64 KB dbuf

    const int tid  = threadIdx.x;
    const int wave = tid >> 6;        // 0..7 (N-dim)
    const int l    = tid & 63;
    const int l15  = l & 15;
    const int kgrp = l >> 4;
    const int l7   = l & 7;
    const int r0   = blockIdx.x * 64; // 64 rows per block, within one batch
    const int bb   = r0 >> 9;

    // --- A staging: 1 swizzled 16B chunk per thread ---
    const int arow = tid >> 3;
    const int ach  = ((tid & 7) ^ (arow & 7)) << 3;   // swizzled k-chunk (elems)
    const float* gAx      = x  + (size_t)(r0 + arow) * D_ + ach;
    unsigned short* gXw   = Xb + (size_t)(r0 + arow) * D_ + ach;

    // --- B staging via global_load_lds (wave-uniform base + lane*16B) ---
    const unsigned short* gB[4];
    unsigned short* lB[4];
    #pragma unroll
    for (int t = 0; t < 4; ++t) {
        const int f   = tid + t * 512;
        const int row = f >> 3;
        const int ch  = ((f & 7) ^ (row & 7)) << 3;
        gB[t] = W1t + (size_t)row * D_ + ch;
        lB[t] = ldsB + t * 4096 + (wave << 9);
    }

    // --- fragment LDS offsets (ushort units), swizzle-consistent ---
    int aoff[4][2], boff[2][2];
    #pragma unroll
    for (int mi = 0; mi < 4; ++mi)
        #pragma unroll
        for (int ks = 0; ks < 2; ++ks)
            aoff[mi][ks] = (mi * 16 + l15) * 64 + (((ks * 4 + kgrp) ^ l7) << 3);
    #pragma unroll
    for (int ni = 0; ni < 2; ++ni)
        #pragma unroll
        for (int ks = 0; ks < 2; ++ks)
            boff[ni][ks] = (wave * 32 + ni * 16 + l15) * 64 + (((ks * 4 + kgrp) ^ l7) << 3);

    // --- b1 / W2 prefetched to registers (no vmcnt strays in main loop) ---
    float b1r[4][2], w2r[4][2];
    #pragma unroll
    for (int n0 = 0; n0 < 4; ++n0)
        #pragma unroll
        for (int ni = 0; ni < 2; ++ni) {
            const int col = n0 * 256 + wave * 32 + ni * 16 + l15;
            b1r[n0][ni] = b1[col];
            w2r[n0][ni] = W2[col];
        }

    float pv[4][4];
    #pragma unroll
    for (int mi = 0; mi < 4; ++mi)
        #pragma unroll
        for (int r = 0; r < 4; ++r) pv[mi][r] = 0.f;

    f32x4 acc[4][2];
    #pragma unroll
    for (int mi = 0; mi < 4; ++mi)
        #pragma unroll
        for (int ni = 0; ni < 2; ++ni)
            acc[mi][ni] = (f32x4){0.f, 0.f, 0.f, 0.f};

#define COMPUTE(BO) do {                                                        \
    _Pragma("unroll")                                                           \
    for (int ks = 0; ks < 2; ++ks) {                                            \
        const short8 a0 = *reinterpret_cast<const short8*>(ldsA + aoff[0][ks]); \
        const short8 a1 = *reinterpret_cast<const short8*>(ldsA + aoff[1][ks]); \
        const short8 a2 = *reinterpret_cast<const short8*>(ldsA + aoff[2][ks]); \
        const short8 a3 = *reinterpret_cast<const short8*>(ldsA + aoff[3][ks]); \
        const short8 bA = *reinterpret_cast<const short8*>(ldsB + (BO) + boff[0][ks]); \
        const short8 bB = *reinterpret_cast<const short8*>(ldsB + (BO) + boff[1][ks]); \
        acc[0][0] = __builtin_amdgcn_mfma_f32_16x16x32_bf16(a0, bA, acc[0][0], 0, 0, 0); \
        acc[1][0] = __builtin_amdgcn_mfma_f32_16x16x32_bf16(a1, bA, acc[1][0], 0, 0, 0); \
        acc[2][0] = __builtin_amdgcn_mfma_f32_16x16x32_bf16(a2, bA, acc[2][0], 0, 0, 0); \
        acc[3][0] = __builtin_amdgcn_mfma_f32_16x16x32_bf16(a3, bA, acc[3][0], 0, 0, 0); \
        acc[0][1] = __builtin_amdgcn_mfma_f32_16x16x32_bf16(a0, bB, acc[0][1], 0, 0, 0); \
        acc[1][1] = __builtin_amdgcn_mfma_f32_16x16x32_bf16(a1, bB, acc[1][1], 0, 0, 0); \
        acc[2][1] = __builtin_amdgcn_mfma_f32_16x16x32_bf16(a2, bB, acc[2][1], 0, 0, 0); \
        acc[3][1] = __builtin_amdgcn_mfma_f32_16x16x32_bf16(a3, bB, acc[3][1], 0, 0, 0); \
    } } while (0)

#define FOLD(N0) do {                                                           \
    _Pragma("unroll")                                                           \
    for (int ni = 0; ni < 2; ++ni) {                                            \
        const float b1v = b1r[N0][ni];                                          \
        const float w2v = w2r[N0][ni];                                          \
        _Pragma("unroll")                                                       \
        for (int mi = 0; mi < 4; ++mi)                                          \
            _Pragma("unroll")                                                   \
            for (int r = 0; r < 4; ++r) {                                       \
                const float h = fast_tanh(acc[mi][ni][r] + b1v);                \
                pv[mi][r] = fmaf(h, w2v, pv[mi][r]);                            \
                acc[mi][ni][r] = 0.f;                                           \
            }                                                                   \
    } } while (0)

    // --- prologue: B[0] async -> buf0; A[0] f32 -> pack ---
    #pragma unroll
    for (int t = 0; t < 4; ++t) async16(gB[t], lB[t]);
    uint4 curA;
    {
        const float4 p0 = *reinterpret_cast<const float4*>(gAx);
        const float4 p1 = *reinterpret_cast<const float4*>(gAx + 4);
        curA = (uint4){pk2(p0.x, p0.y), pk2(p0.z, p0.w),
                       pk2(p1.x, p1.y), pk2(p1.z, p1.w)};
    }
    uint4 nxA;

    // ---- sweep 0, it = 0..14 (fused cast; f32 A prefetch; write-through) ----
    for (int it = 0; it < 15; ++it) {
        const int bo = (it & 1) << 14;     // ushort offset into ldsB dbuf
        const int nb = bo ^ 16384;
        FENCE; __builtin_amdgcn_s_barrier(); FENCE;               // X (WAR)
        *reinterpret_cast<uint4*>(ldsA + tid * 8) = curA;          // publish A[it]
        *reinterpret_cast<uint4*>(gXw + (it << 6)) = curA;         // write-through
        const int ak = (it + 1) << 6;
        const float4 q0 = *reinterpret_cast<const float4*>(gAx + ak);
        const float4 q1 = *reinterpret_cast<const float4*>(gAx + ak + 4);
        #pragma unroll
        for (int t = 0; t < 4; ++t) async16(gB[t] + ak, lB[t] + nb);
        asm volatile("s_waitcnt vmcnt(7)" ::: "memory");           // retire B[it]
        asm volatile("s_waitcnt lgkmcnt(0)" ::: "memory");         // A published
        __builtin_amdgcn_s_barrier();                              // Y (RAW)
        __builtin_amdgcn_sched_barrier(0);
        __builtin_amdgcn_s_setprio(1);
        COMPUTE(bo);
        __builtin_amdgcn_s_setprio(0);
        curA = (uint4){pk2(q0.x, q0.y), pk2(q0.z, q0.w),           // pack in shadow
                       pk2(q1.x, q1.y), pk2(q1.z, q1.w)};
    }

    // ---- it = 15: last cast iter; fold n0=0; switch A source to Xb ----
    {
        FENCE; __builtin_amdgcn_s_barrier(); FENCE;
        *reinterpret_cast<uint4*>(ldsA + tid * 8) = curA;
        *reinterpret_cast<uint4*>(gXw + (15 << 6)) = curA;
        nxA = *reinterpret_cast<const uint4*>(gXw);                // A[16]=k0 0 chunk
        #pragma unroll
        for (int t = 0; t < 4; ++t) async16(gB[t] + 256 * D_, lB[t]);  // B[16]->buf0
        asm volatile("s_waitcnt vmcnt(6)" ::: "memory");
        asm volatile("s_waitcnt lgkmcnt(0)" ::: "memory");
        __builtin_amdgcn_s_barrier();
        __builtin_amdgcn_sched_barrier(0);
        __builtin_amdgcn_s_setprio(1);
        COMPUTE(16384);
        __builtin_amdgcn_s_setprio(0);
        FOLD(0);
    }

    // ---- sweeps 1..3 (A from self-written Xb; pure counted pipeline) ----
    #pragma unroll
    for (int s = 1; s < 4; ++s) {
        const int kkmax = (s == 3) ? 15 : 16;
        for (int kk = 0; kk < kkmax; ++kk) {
            const int it = s * 16 + kk;
            const int bo = (it & 1) << 14;
            const int nb = bo ^ 16384;
            FENCE; __builtin_amdgcn_s_barrier(); FENCE;            // X
            *reinterpret_cast<uint4*>(ldsA + tid * 8) = nxA;        // publish A[it]
            const int j  = it + 1;
            const int jk = (j & 15) << 6;
            const size_t jofs = (size_t)(j >> 4) * (256 * D_) + jk;
            nxA = *reinterpret_cast<const uint4*>(gXw + jk);        // A[it+1]
            #pragma unroll
            for (int t = 0; t < 4; ++t) async16(gB[t] + jofs, lB[t] + nb);
            asm volatile("s_waitcnt vmcnt(5)" ::: "memory");        // retire B[it]
            asm volatile("s_waitcnt lgkmcnt(0)" ::: "memory");
            __builtin_amdgcn_s_barrier();                           // Y
            __builtin_amdgcn_sched_barrier(0);
            __builtin_amdgcn_s_setprio(1);
            COMPUTE(bo);
            __builtin_amdgcn_s_setprio(0);
            if (kk == 15) FOLD(s);   // s compile-time (outer unrolled)
        }
    }

    // ---- it = 63 ----
    {
        FENCE; __builtin_amdgcn_s_barrier(); FENCE;
        *reinterpret_cast<uint4*>(ldsA + tid * 8) = nxA;
        asm volatile("s_waitcnt vmcnt(0)" ::: "memory");
        asm volatile("s_waitcnt lgkmcnt(0)" ::: "memory");
        __builtin_amdgcn_s_barrier();
        __builtin_amdgcn_sched_barrier(0);
        __builtin_amdgcn_s_setprio(1);
        COMPUTE(16384);
        __builtin_amdgcn_s_setprio(0);
        FOLD(3);
    }
#undef COMPUTE
#undef FOLD

    // --- epilogue (scratch aliased onto ldsA) ---
    __syncthreads();
    float* pv_part = reinterpret_cast<float*>(ldsA);   // [8][64]
    float* vrow    = pv_part + 512;                    // [64]

    // reduce pv over the 16 col-lanes (C/D: row = kgrp*4+r, col = l15)
    #pragma unroll
    for (int mi = 0; mi < 4; ++mi)
        #pragma unroll
        for (int r = 0; r < 4; ++r) {
            float s = pv[mi][r];
            s += __shfl_xor(s, 1);
            s += __shfl_xor(s, 2);
            s += __shfl_xor(s, 4);
            s += __shfl_xor(s, 8);
            if (l15 == 0) pv_part[wave * 64 + mi * 16 + kgrp * 4 + r] = s;
        }
    __syncthreads();
    if (tid < 64) {
        float s = b2[0];
        #pragma unroll
        for (int w = 0; w < 8; ++w) s += pv_part[w * 64 + tid];
        const float sg = 1.0f / (1.0f + __expf(-s));
        const float v = sg * mask[r0 + tid];
        val_ws[r0 + tid] = v;
        vrow[tid] = v;
    }
    __syncthreads();

    // unnormalized pooled: pooled[bb][k] += sum_rows Xb[r][k]*val[r]
    const int kc = tid << 1;
    float a0 = 0.f, a1 = 0.f;
    for (int row = 0; row < 64; ++row) {
        const float v = vrow[row];
        const uint32_t u = *reinterpret_cast<const uint32_t*>(
            Xb + (size_t)(r0 + row) * D_ + kc);
        a0 = fmaf(__builtin_bit_cast(float, u << 16), v, a0);
        a1 = fmaf(__builtin_bit_cast(float, u & 0xffff0000u), v, a1);
    }
    atomicAdd(&pooled[bb * D_ + kc], a0);
    atomicAdd(&pooled[bb * D_ + kc + 1], a1);
}

// ---------------------------------------------------------------------------
// Fallback fp32 path (used only if ws too small)
// ---------------------------------------------------------------------------
#define MT 64
#define KT 32
#define PAD 68

__global__ __launch_bounds__(256) void score_kernel_fp32(
    const float* __restrict__ x, const float* __restrict__ mask,
    const float* __restrict__ W1, const float* __restrict__ b1,
    const float* __restrict__ W2, const float* __restrict__ b2,
    float* __restrict__ val_ws, float* __restrict__ pooled)
{
    __shared__ float As[KT][PAD];
    __shared__ float Bs[KT][PAD];
    __shared__ float red[MT][17];
    __shared__ float vrow[MT];

    const int tid = threadIdx.x;
    const int tx = tid & 15;
    const int ty = tid >> 4;
    const int r0 = blockIdx.x * MT;
    const int b  = r0 >> 9;

    float pv[4] = {0.f, 0.f, 0.f, 0.f};

    for (int n0 = 0; n0 < D_; n0 += 64) {
        float acc[4][4];
        #pragma unroll
        for (int i = 0; i < 4; ++i)
            #pragma unroll
            for (int j = 0; j < 4; ++j) acc[i][j] = 0.f;

        for (int k0 = 0; k0 < D_; k0 += KT) {
            #pragma unroll
            for (int ll = 0; ll < 2; ++ll) {
                const int f   = tid + ll * 256;
                const int row = f >> 3;
                const int k4  = (f & 7) << 2;
                const float4 xv = *reinterpret_cast<const float4*>(
                    &x[(size_t)(r0 + row) * D_ + k0 + k4]);
                As[k4 + 0][row] = xv.x;
                As[k4 + 1][row] = xv.y;
                As[k4 + 2][row] = xv.z;
                As[k4 + 3][row] = xv.w;
            }
            #pragma unroll
            for (int ll = 0; ll < 2; ++ll) {
                const int f  = tid + ll * 256;
                const int k  = f >> 4;
                const int n4 = (f & 15) << 2;
                const float4 wv = *reinterpret_cast<const float4*>(
                    &W1[(size_t)(k0 + k) * D_ + n0 + n4]);
                *reinterpret_cast<float4*>(&Bs[k][n4]) = wv;
            }
            __syncthreads();
            #pragma unroll
            for (int kk = 0; kk < KT; ++kk) {
                const float4 a4 = *reinterpret_cast<const float4*>(&As[kk][ty << 2]);
                const float4 b4 = *reinterpret_cast<const float4*>(&Bs[kk][tx << 2]);
                const float av[4] = {a4.x, a4.y, a4.z, a4.w};
                const float bv[4] = {b4.x, b4.y, b4.z, b4.w};
                #pragma unroll
                for (int i = 0; i < 4; ++i)
                    #pragma unroll
                    for (int j = 0; j < 4; ++j)
                        acc[i][j] = fmaf(av[i], bv[j], acc[i][j]);
            }
            __syncthreads();
        }
        #pragma unroll
        for (int j = 0; j < 4; ++j) {
            const int col = n0 + (tx << 2) + j;
            const float b1v = b1[col];
            const float w2v = W2[col];
            #pragma unroll
            for (int i = 0; i < 4; ++i) {
                const float h = fast_tanh(acc[i][j] + b1v);
                pv[i] = fmaf(h, w2v, pv[i]);
            }
        }
    }

    #pragma unroll
    for (int i = 0; i < 4; ++i) red[(ty << 2) + i][tx] = pv[i];
    __syncthreads();

    if (tid < MT) {
        float s = 0.f;
        #pragma unroll
        for (int t = 0; t < 16; ++t) s += red[tid][t];
        const float z  = s + b2[0];
        const float sg = 1.0f / (1.0f + __expf(-z));
        const float v  = sg * mask[r0 + tid];
        val_ws[r0 + tid] = v;
        vrow[tid] = v;
    }
    __syncthreads();

    const int k = tid << 2;
    float a0 = 0.f, a1 = 0.f, a2 = 0.f, a3 = 0.f;
    for (int row = 0; row < MT; ++row) {
        const float v = vrow[row];
        const float4 xv = *reinterpret_cast<const float4*>(
            &x[(size_t)(r0 + row) * D_ + k]);
        a0 = fmaf(xv.x, v, a0);
        a1 = fmaf(xv.y, v, a1);
        a2 = fmaf(xv.z, v, a2);
        a3 = fmaf(xv.w, v, a3);
    }
    float* pb = &pooled[b * D_ + k];
    atomicAdd(pb + 0, a0);
    atomicAdd(pb + 1, a1);
    atomicAdd(pb + 2, a2);
    atomicAdd(pb + 3, a3);
}

__global__ __launch_bounds__(256) void finalize_kernel(
    const float* __restrict__ val_ws, const float* __restrict__ pooled,
    const float* __restrict__ W3, const float* __restrict__ b3,
    float* __restrict__ out)
{
    __shared__ float sred[256];
    const int b = blockIdx.x;
    const int tid = threadIdx.x;

    const float v0 = val_ws[b * J_ + tid];
    const float v1 = val_ws[b * J_ + 256 + tid];
    sred[tid] = v0 + v1;
    __syncthreads();
    for (int s = 128; s > 0; s >>= 1) {
        if (tid < s) sred[tid] += sred[tid + s];
        __syncthreads();
    }
    const float inv = 1.0f / sred[0];

    out[192 + b * J_ + tid]       = v0 * inv;
    out[192 + b * J_ + 256 + tid] = v1 * inv;

    const int k = tid << 2;
    float acc3[3] = {0.f, 0.f, 0.f};
    #pragma unroll
    for (int c = 0; c < 4; ++c) {
        const float p = pooled[b * D_ + k + c] * inv;
        acc3[0] = fmaf(p, W3[(k + c) * 3 + 0], acc3[0]);
        acc3[1] = fmaf(p, W3[(k + c) * 3 + 1], acc3[1]);
        acc3[2] = fmaf(p, W3[(k + c) * 3 + 2], acc3[2]);
    }
    for (int o = 0; o < 3; ++o) {
        __syncthreads();
        sred[tid] = acc3[o];
        __syncthreads();
        for (int s = 128; s > 0; s >>= 1) {
            if (tid < s) sred[tid] += sred[tid + s];
            __syncthreads();
        }
        if (tid == 0) out[b * 3 + o] = sred[0] + b3[o];
    }
}

extern "C" void kernel_launch(void* const* d_in, const int* in_sizes, int n_in,
                              void* d_out, int out_size, void* d_ws, size_t ws_size,
                              hipStream_t stream) {
    const float* x    = (const float*)d_in[0];
    const float* mask = (const float*)d_in[1];
    const float* W1   = (const float*)d_in[2];
    const float* b1   = (const float*)d_in[3];
    const float* W2   = (const float*)d_in[4];
    const float* b2   = (const float*)d_in[5];
    const float* W3   = (const float*)d_in[6];
    const float* b3   = (const float*)d_in[7];
    float* out = (float*)d_out;

    const size_t XB_BYTES   = (size_t)B_ * J_ * D_ * 2;   // 67,108,864
    const size_t W1T_BYTES  = (size_t)D_ * D_ * 2;        //  2,097,152
    const size_t VAL_BYTES  = (size_t)B_ * J_ * 4;        //    131,072
    const size_t POOL_BYTES = (size_t)B_ * D_ * 4;        //    262,144
    const size_t NEED = XB_BYTES + W1T_BYTES + VAL_BYTES + POOL_BYTES;

    if (ws_size >= NEED) {
        unsigned short* Xb  = (unsigned short*)d_ws;
        unsigned short* W1t = (unsigned short*)((char*)d_ws + XB_BYTES);
        float* val_ws = (float*)((char*)d_ws + XB_BYTES + W1T_BYTES);
        float* pooled = (float*)((char*)d_ws + XB_BYTES + W1T_BYTES + VAL_BYTES);

        prep_kernel<<<1024, 256, 0, stream>>>(W1, W1t, pooled);
        gemm_score_kernel<<<512, 512, 0, stream>>>(x, Xb, W1t, b1, W2, b2, mask,
                                                   val_ws, pooled);
        finalize_kernel<<<B_, 256, 0, stream>>>(val_ws, pooled, W3, b3, out);
    } else {
        float* val_ws = (float*)d_ws;
        float* pooled = val_ws + B_ * J_;
        hipMemsetAsync(pooled, 0, POOL_BYTES, stream);
        score_kernel_fp32<<<(B_ * J_) / MT, 256, 0, stream>>>(
            x, mask, W1, b1, W2, b2, val_ws, pooled);
        finalize_kernel<<<B_, 256, 0, stream>>>(val_ws, pooled, W3, b3, out);
    }
}

// Round 4
// 297.763 us; speedup vs baseline: 1.1857x; 1.1857x over previous
//
#include <hip/hip_runtime.h>
#include <math.h>
#include <stdint.h>

#define B_ 64
#define J_ 512
#define D_ 1024

typedef __attribute__((ext_vector_type(8))) short short8;
typedef __attribute__((ext_vector_type(4))) float f32x4;

#define GLOBAL_AS __attribute__((address_space(1)))
#define LDS_AS    __attribute__((address_space(3)))

__device__ __forceinline__ void async16(const void* g, void* l) {
    __builtin_amdgcn_global_load_lds((const GLOBAL_AS uint32_t*)g,
                                     (LDS_AS uint32_t*)l, 16, 0, 0);
}

// tanh(x) = 1 - 2/(1+e^{2x}); saturates correctly for |x| large.
__device__ __forceinline__ float fast_tanh(float x) {
    return 1.0f - 2.0f / (1.0f + __expf(2.0f * x));
}

// fp32 -> bf16 round-to-nearest-even
__device__ __forceinline__ unsigned short f2bf(float f) {
    uint32_t u = __builtin_bit_cast(uint32_t, f);
    u += 0x7fffu + ((u >> 16) & 1u);
    return (unsigned short)(u >> 16);
}

// ---------------------------------------------------------------------------
// cast_x: x f32 -> Xb bf16, linear (perfectly coalesced 16B stores).
// ---------------------------------------------------------------------------
__global__ __launch_bounds__(256) void cast_x_kernel(const float* __restrict__ x,
                                                     unsigned short* __restrict__ xb) {
    const size_t i = ((size_t)blockIdx.x * 256 + threadIdx.x) * 8;
    const float4 v0 = *reinterpret_cast<const float4*>(x + i);
    const float4 v1 = *reinterpret_cast<const float4*>(x + i + 4);
    uint4 o;
    o.x = (uint32_t)f2bf(v0.x) | ((uint32_t)f2bf(v0.y) << 16);
    o.y = (uint32_t)f2bf(v0.z) | ((uint32_t)f2bf(v0.w) << 16);
    o.z = (uint32_t)f2bf(v1.x) | ((uint32_t)f2bf(v1.y) << 16);
    o.w = (uint32_t)f2bf(v1.z) | ((uint32_t)f2bf(v1.w) << 16);
    *reinterpret_cast<uint4*>(xb + i) = o;
}

// ---------------------------------------------------------------------------
// prep: W1[k][n] fp32 -> W1t[n][k] bf16, fused with zeroing of pooled accum.
// ---------------------------------------------------------------------------
__global__ __launch_bounds__(256) void prep_kernel(const float* __restrict__ W1,
                                                   unsigned short* __restrict__ W1t,
                                                   float* __restrict__ pooled) {
    __shared__ float t[32][33];
    const int b   = blockIdx.x;
    const int tid = threadIdx.x;
    if (b < 256) pooled[b * 256 + tid] = 0.f;   // 64*1024 floats total
    const int bx = b & 31, by = b >> 5;
    const int tx = tid & 31, ty = tid >> 5;
    const int n = bx * 32 + tx;
    for (int i = ty; i < 32; i += 8)
        t[i][tx] = W1[(size_t)(by * 32 + i) * D_ + n];
    __syncthreads();
    const int k = by * 32 + tx;
    for (int i = ty; i < 32; i += 8)
        W1t[(size_t)(bx * 32 + i) * D_ + k] = f2bf(t[tx][i]);
}

// ---------------------------------------------------------------------------
// gemm+score kernel — round-0 sync structure (2 __syncthreads per k-step,
// single-buffered LDS, global_load_lds staging), new geometry:
//   block tile 64(M) x 512(N) per n0-step (2 sweeps), BK=64,
//   8 waves in 1x8 over N, wave-tile 64x64 (4mi x 4ni).
// LDS-read per wave per k-step: 16 x ds_read_b128 feed 32 MFMAs
// (0.5 KB/MFMA vs round-0's 0.75) and barrier count halves.
// ---------------------------------------------------------------------------
__global__ __launch_bounds__(512, 4) void gemm_score_kernel(
    const unsigned short* __restrict__ Xb, const unsigned short* __restrict__ W1t,
    const float* __restrict__ b1, const float* __restrict__ W2,
    const float* __restrict__ b2, const float* __restrict__ mask,
    float* __restrict__ val_ws, float* __restrict__ pooled)
{
    __shared__ __align__(16) unsigned short ldsA[64 * 64];     //  8 KB [m][k] swz
    __shared__ __align__(16) unsigned short ldsB[512 * 64];    // 64 KB [n][k] swz

    const int tid  = threadIdx.x;
    const int wave = tid >> 6;        // 0..7 (N-dim)
    const int l    = tid & 63;
    const int l15  = l & 15;
    const int kgrp = l >> 4;
    const int l7   = l & 7;
    const int r0   = blockIdx.x * 64; // 64 rows per block, within one batch
    const int bb   = r0 >> 9;

    // --- A staging: 1 swizzled 16B chunk per thread ---
    const int arow = tid >> 3;
    const unsigned short* gA = Xb + (size_t)(r0 + arow) * D_
                                  + (((tid & 7) ^ (arow & 7)) << 3);
    unsigned short* lA = ldsA + (wave << 9);          // HW adds lane*16B

    // --- B staging: 8 chunks/thread; rows brow0 + t*64 (+ n0*512) ---
    // f = tid + t*512: f&7 == tid&7 and (f>>3)&7 == (tid>>3)&7, so the
    // swizzled chunk offset is t-invariant -> single base + t*64*D_.
    const unsigned short* gB0 = W1t + (size_t)arow * D_
                                    + (((tid & 7) ^ (arow & 7)) << 3);
    unsigned short* lB0 = ldsB + (wave << 9);

    // --- fragment LDS base offsets (ushort units), swizzle-consistent ---
    // aoff[mi][ks] = abase[ks] + mi*1024 ; boff[ni][ks] = bbase[ks] + ni*1024
    int abase[2], bbase[2];
    #pragma unroll
    for (int ks = 0; ks < 2; ++ks) {
        const int swz = (((ks * 4 + kgrp) ^ l7) << 3);
        abase[ks] = l15 * 64 + swz;
        bbase[ks] = (wave * 64 + l15) * 64 + swz;
    }

    float pv[4][4];
    #pragma unroll
    for (int mi = 0; mi < 4; ++mi)
        #pragma unroll
        for (int r = 0; r < 4; ++r) pv[mi][r] = 0.f;

    for (int n0 = 0; n0 < 2; ++n0) {
        f32x4 acc[4][4];
        #pragma unroll
        for (int mi = 0; mi < 4; ++mi)
            #pragma unroll
            for (int ni = 0; ni < 4; ++ni)
                acc[mi][ni] = (f32x4){0.f, 0.f, 0.f, 0.f};

        const size_t bofs = (size_t)n0 * 512 * D_;
        for (int k0 = 0; k0 < D_; k0 += 64) {
            async16(gA + k0, lA);
            #pragma unroll
            for (int t = 0; t < 8; ++t)
                async16(gB0 + bofs + (size_t)t * 64 * D_ + k0, lB0 + t * 4096);
            __syncthreads();
            #pragma unroll
            for (int ks = 0; ks < 2; ++ks) {
                const short8 a0 = *reinterpret_cast<const short8*>(ldsA + abase[ks]);
                const short8 a1 = *reinterpret_cast<const short8*>(ldsA + abase[ks] + 1024);
                const short8 a2 = *reinterpret_cast<const short8*>(ldsA + abase[ks] + 2048);
                const short8 a3 = *reinterpret_cast<const short8*>(ldsA + abase[ks] + 3072);
                #pragma unroll
                for (int ni = 0; ni < 4; ++ni) {
                    const short8 bv = *reinterpret_cast<const short8*>(
                        ldsB + bbase[ks] + ni * 1024);
                    acc[0][ni] = __builtin_amdgcn_mfma_f32_16x16x32_bf16(a0, bv, acc[0][ni], 0, 0, 0);
                    acc[1][ni] = __builtin_amdgcn_mfma_f32_16x16x32_bf16(a1, bv, acc[1][ni], 0, 0, 0);
                    acc[2][ni] = __builtin_amdgcn_mfma_f32_16x16x32_bf16(a2, bv, acc[2][ni], 0, 0, 0);
                    acc[3][ni] = __builtin_amdgcn_mfma_f32_16x16x32_bf16(a3, bv, acc[3][ni], 0, 0, 0);
                }
            }
            __syncthreads();
        }

        // fold this 512-col n-tile of h into pv (h never materialized)
        #pragma unroll
        for (int ni = 0; ni < 4; ++ni) {
            const int col = n0 * 512 + wave * 64 + ni * 16 + l15;
            const float b1v = b1[col];
            const float w2v = W2[col];
            #pragma unroll
            for (int mi = 0; mi < 4; ++mi)
                #pragma unroll
                for (int r = 0; r < 4; ++r) {
                    const float h = fast_tanh(acc[mi][ni][r] + b1v);
                    pv[mi][r] = fmaf(h, w2v, pv[mi][r]);
                }
        }
    }

    // --- epilogue (scratch aliased onto ldsB; all MFMA reads are behind the
    //     final __syncthreads of the k-loop) ---
    float* pv_part = reinterpret_cast<float*>(ldsB);   // [8][64]
    float* vrow    = pv_part + 512;                    // [64]

    // reduce pv over the 16 col-lanes (C/D: row = kgrp*4+r, col = l15)
    #pragma unroll
    for (int mi = 0; mi < 4; ++mi)
        #pragma unroll
        for (int r = 0; r < 4; ++r) {
            float s = pv[mi][r];
            s += __shfl_xor(s, 1);
            s += __shfl_xor(s, 2);
            s += __shfl_xor(s, 4);
            s += __shfl_xor(s, 8);
            if (l15 == 0) pv_part[wave * 64 + mi * 16 + kgrp * 4 + r] = s;
        }
    __syncthreads();
    if (tid < 64) {
        float s = b2[0];
        #pragma unroll
        for (int w = 0; w < 8; ++w) s += pv_part[w * 64 + tid];
        const float sg = 1.0f / (1.0f + __expf(-s));
        const float v = sg * mask[r0 + tid];
        val_ws[r0 + tid] = v;
        vrow[tid] = v;
    }
    __syncthreads();

    // unnormalized pooled: pooled[bb][k] += sum_rows Xb[r][k]*val[r]
    const int kc = tid << 1;
    float a0 = 0.f, a1 = 0.f;
    for (int row = 0; row < 64; ++row) {
        const float v = vrow[row];
        const uint32_t u = *reinterpret_cast<const uint32_t*>(
            Xb + (size_t)(r0 + row) * D_ + kc);
        a0 = fmaf(__builtin_bit_cast(float, u << 16), v, a0);
        a1 = fmaf(__builtin_bit_cast(float, u & 0xffff0000u), v, a1);
    }
    atomicAdd(&pooled[bb * D_ + kc], a0);
    atomicAdd(&pooled[bb * D_ + kc + 1], a1);
}

// ---------------------------------------------------------------------------
// Fallback fp32 path (used only if ws too small)
// ---------------------------------------------------------------------------
#define MT 64
#define KT 32
#define PAD 68

__global__ __launch_bounds__(256) void score_kernel_fp32(
    const float* __restrict__ x, const float* __restrict__ mask,
    const float* __restrict__ W1, const float* __restrict__ b1,
    const float* __restrict__ W2, const float* __restrict__ b2,
    float* __restrict__ val_ws, float* __restrict__ pooled)
{
    __shared__ float As[KT][PAD];
    __shared__ float Bs[KT][PAD];
    __shared__ float red[MT][17];
    __shared__ float vrow[MT];

    const int tid = threadIdx.x;
    const int tx = tid & 15;
    const int ty = tid >> 4;
    const int r0 = blockIdx.x * MT;
    const int b  = r0 >> 9;

    float pv[4] = {0.f, 0.f, 0.f, 0.f};

    for (int n0 = 0; n0 < D_; n0 += 64) {
        float acc[4][4];
        #pragma unroll
        for (int i = 0; i < 4; ++i)
            #pragma unroll
            for (int j = 0; j < 4; ++j) acc[i][j] = 0.f;

        for (int k0 = 0; k0 < D_; k0 += KT) {
            #pragma unroll
            for (int ll = 0; ll < 2; ++ll) {
                const int f   = tid + ll * 256;
                const int row = f >> 3;
                const int k4  = (f & 7) << 2;
                const float4 xv = *reinterpret_cast<const float4*>(
                    &x[(size_t)(r0 + row) * D_ + k0 + k4]);
                As[k4 + 0][row] = xv.x;
                As[k4 + 1][row] = xv.y;
                As[k4 + 2][row] = xv.z;
                As[k4 + 3][row] = xv.w;
            }
            #pragma unroll
            for (int ll = 0; ll < 2; ++ll) {
                const int f  = tid + ll * 256;
                const int k  = f >> 4;
                const int n4 = (f & 15) << 2;
                const float4 wv = *reinterpret_cast<const float4*>(
                    &W1[(size_t)(k0 + k) * D_ + n0 + n4]);
                *reinterpret_cast<float4*>(&Bs[k][n4]) = wv;
            }
            __syncthreads();
            #pragma unroll
            for (int kk = 0; kk < KT; ++kk) {
                const float4 a4 = *reinterpret_cast<const float4*>(&As[kk][ty << 2]);
                const float4 b4 = *reinterpret_cast<const float4*>(&Bs[kk][tx << 2]);
                const float av[4] = {a4.x, a4.y, a4.z, a4.w};
                const float bv[4] = {b4.x, b4.y, b4.z, b4.w};
                #pragma unroll
                for (int i = 0; i < 4; ++i)
                    #pragma unroll
                    for (int j = 0; j < 4; ++j)
                        acc[i][j] = fmaf(av[i], bv[j], acc[i][j]);
            }
            __syncthreads();
        }
        #pragma unroll
        for (int j = 0; j < 4; ++j) {
            const int col = n0 + (tx << 2) + j;
            const float b1v = b1[col];
            const float w2v = W2[col];
            #pragma unroll
            for (int i = 0; i < 4; ++i) {
                const float h = fast_tanh(acc[i][j] + b1v);
                pv[i] = fmaf(h, w2v, pv[i]);
            }
        }
    }

    #pragma unroll
    for (int i = 0; i < 4; ++i) red[(ty << 2) + i][tx] = pv[i];
    __syncthreads();

    if (tid < MT) {
        float s = 0.f;
        #pragma unroll
        for (int t = 0; t < 16; ++t) s += red[tid][t];
        const float z  = s + b2[0];
        const float sg = 1.0f / (1.0f + __expf(-z));
        const float v  = sg * mask[r0 + tid];
        val_ws[r0 + tid] = v;
        vrow[tid] = v;
    }
    __syncthreads();

    const int k = tid << 2;
    float a0 = 0.f, a1 = 0.f, a2 = 0.f, a3 = 0.f;
    for (int row = 0; row < MT; ++row) {
        const float v = vrow[row];
        const float4 xv = *reinterpret_cast<const float4*>(
            &x[(size_t)(r0 + row) * D_ + k]);
        a0 = fmaf(xv.x, v, a0);
        a1 = fmaf(xv.y, v, a1);
        a2 = fmaf(xv.z, v, a2);
        a3 = fmaf(xv.w, v, a3);
    }
    float* pb = &pooled[b * D_ + k];
    atomicAdd(pb + 0, a0);
    atomicAdd(pb + 1, a1);
    atomicAdd(pb + 2, a2);
    atomicAdd(pb + 3, a3);
}

__global__ __launch_bounds__(256) void finalize_kernel(
    const float* __restrict__ val_ws, const float* __restrict__ pooled,
    const float* __restrict__ W3, const float* __restrict__ b3,
    float* __restrict__ out)
{
    __shared__ float sred[256];
    const int b = blockIdx.x;
    const int tid = threadIdx.x;

    const float v0 = val_ws[b * J_ + tid];
    const float v1 = val_ws[b * J_ + 256 + tid];
    sred[tid] = v0 + v1;
    __syncthreads();
    for (int s = 128; s > 0; s >>= 1) {
        if (tid < s) sred[tid] += sred[tid + s];
        __syncthreads();
    }
    const float inv = 1.0f / sred[0];

    out[192 + b * J_ + tid]       = v0 * inv;
    out[192 + b * J_ + 256 + tid] = v1 * inv;

    const int k = tid << 2;
    float acc3[3] = {0.f, 0.f, 0.f};
    #pragma unroll
    for (int c = 0; c < 4; ++c) {
        const float p = pooled[b * D_ + k + c] * inv;
        acc3[0] = fmaf(p, W3[(k + c) * 3 + 0], acc3[0]);
        acc3[1] = fmaf(p, W3[(k + c) * 3 + 1], acc3[1]);
        acc3[2] = fmaf(p, W3[(k + c) * 3 + 2], acc3[2]);
    }
    for (int o = 0; o < 3; ++o) {
        __syncthreads();
        sred[tid] = acc3[o];
        __syncthreads();
        for (int s = 128; s > 0; s >>= 1) {
            if (tid < s) sred[tid] += sred[tid + s];
            __syncthreads();
        }
        if (tid == 0) out[b * 3 + o] = sred[0] + b3[o];
    }
}

extern "C" void kernel_launch(void* const* d_in, const int* in_sizes, int n_in,
                              void* d_out, int out_size, void* d_ws, size_t ws_size,
                              hipStream_t stream) {
    const float* x    = (const float*)d_in[0];
    const float* mask = (const float*)d_in[1];
    const float* W1   = (const float*)d_in[2];
    const float* b1   = (const float*)d_in[3];
    const float* W2   = (const float*)d_in[4];
    const float* b2   = (const float*)d_in[5];
    const float* W3   = (const float*)d_in[6];
    const float* b3   = (const float*)d_in[7];
    float* out = (float*)d_out;

    const size_t XB_BYTES   = (size_t)B_ * J_ * D_ * 2;   // 67,108,864
    const size_t W1T_BYTES  = (size_t)D_ * D_ * 2;        //  2,097,152
    const size_t VAL_BYTES  = (size_t)B_ * J_ * 4;        //    131,072
    const size_t POOL_BYTES = (size_t)B_ * D_ * 4;        //    262,144
    const size_t NEED = XB_BYTES + W1T_BYTES + VAL_BYTES + POOL_BYTES;

    if (ws_size >= NEED) {
        unsigned short* Xb  = (unsigned short*)d_ws;
        unsigned short* W1t = (unsigned short*)((char*)d_ws + XB_BYTES);
        float* val_ws = (float*)((char*)d_ws + XB_BYTES + W1T_BYTES);
        float* pooled = (float*)((char*)d_ws + XB_BYTES + W1T_BYTES + VAL_BYTES);

        prep_kernel<<<1024, 256, 0, stream>>>(W1, W1t, pooled);
        cast_x_kernel<<<(B_ * J_ * D_) / (256 * 8), 256, 0, stream>>>(x, Xb);
        gemm_score_kernel<<<512, 512, 0, stream>>>(Xb, W1t, b1, W2, b2, mask,
                                                   val_ws, pooled);
        finalize_kernel<<<B_, 256, 0, stream>>>(val_ws, pooled, W3, b3, out);
    } else {
        float* val_ws = (float*)d_ws;
        float* pooled = val_ws + B_ * J_;
        hipMemsetAsync(pooled, 0, POOL_BYTES, stream);
        score_kernel_fp32<<<(B_ * J_) / MT, 256, 0, stream>>>(
            x, mask, W1, b1, W2, b2, val_ws, pooled);
        finalize_kernel<<<B_, 256, 0, stream>>>(val_ws, pooled, W3, b3, out);
    }
}